// Round 10
// baseline (83.126 us; speedup 1.0000x reference)
//
#include <hip/hip_runtime.h>
#include <math.h>

// Problem shape (fixed by reference setup_inputs):
//   feature_map: (B=8, D=256, H=128, W=128) fp32
//   para_code:   (8, 256)
//   W1 (256,256) b1(256) | Ws (256,256) bs(256) | Wr (256,256) br(256)
//   Wt (256,512) bt(512)
// Output: (8, 256, 128, 128) fp32

#define B_  8
#define D_  256
#define H_  128
#define W_  128
#define PC_ 256
#define PI_F 3.14159f
#define LP_ 129   // padded LDS row stride: 129 % 32 == 1 -> row-step gathers hit
                  // consecutive banks (128 % 32 == 0 was a 32-way conflict for
                  // rotation-dominant planes)

// ------------- Kernel 1: fused p = relu(para@W1+b1) -> heads ----------------
__global__ void k_params(const float* __restrict__ para,
                         const float* __restrict__ W1, const float* __restrict__ b1,
                         const float* __restrict__ Ws, const float* __restrict__ bs,
                         const float* __restrict__ Wr, const float* __restrict__ br,
                         const float* __restrict__ Wt, const float* __restrict__ bt,
                         float* __restrict__ sc_o, float* __restrict__ c_o,
                         float* __restrict__ s_o,  float* __restrict__ tx_o,
                         float* __restrict__ ty_o) {
    __shared__ float sp[PC_];   // para row
    __shared__ float pp[PC_];   // relu'd hidden
    const int b = blockIdx.x;
    const int which = blockIdx.y;
    const int d = threadIdx.x;
    sp[d] = para[b * PC_ + d];
    __syncthreads();

    float acc = b1[d];
#pragma unroll 8
    for (int k = 0; k < PC_; ++k) {
        acc = fmaf(sp[k], W1[k * PC_ + d], acc);
    }
    pp[d] = fmaxf(acc, 0.0f);
    __syncthreads();

    const int o = b * D_ + d;
    if (which == 0) {
        float as = bs[d];
        float ar = br[d];
#pragma unroll 8
        for (int k = 0; k < PC_; ++k) {
            const float pk = pp[k];
            as = fmaf(pk, Ws[k * PC_ + d], as);
            ar = fmaf(pk, Wr[k * PC_ + d], ar);
        }
        const float scale = 2.0f / (1.0f + expf(-as));      // sigmoid * 2
        const float ang   = tanhf(ar) * PI_F;
        sc_o[o] = scale;
        c_o[o]  = cosf(ang);
        s_o[o]  = sinf(ang);
    } else {
        const float2* __restrict__ Wt2 = (const float2*)Wt;  // (256,256) float2
        float t0 = bt[2 * d];
        float t1 = bt[2 * d + 1];
#pragma unroll 8
        for (int k = 0; k < PC_; ++k) {
            const float pk = pp[k];
            const float2 wt = Wt2[k * PC_ + d];
            t0 = fmaf(pk, wt.x, t0);
            t1 = fmaf(pk, wt.y, t1);
        }
        tx_o[o] = tanhf(t0);
        ty_o[o] = tanhf(t1);
    }
}

// ------------- Kernel 2: affine grid-sample via padded LDS plane ------------
// Round-9 shell (2048 blocks x 512 thr, 1 plane/block, 2 blocks/CU), ONE
// change: __builtin_amdgcn_sched_barrier(0) between the tap-load phase and
// the lerp phase of each 8-pixel batch. Rounds 3-9 proved the scheduler
// sinks each ds_read2 to just before its consumer regardless of source ILP
// or VGPR budget (chose 20/64/52 regs under 64/128/512 budgets) -> per-pixel
// exposed LDS latency. The fence forces all 16 ds_read2 of a batch to issue
// before any lerp -> counted-lgkmcnt drain at LDS throughput.
__global__ __launch_bounds__(512, 4)
void k_sample(const float* __restrict__ fm,
              const float* __restrict__ sc_a, const float* __restrict__ c_a,
              const float* __restrict__ s_a,  const float* __restrict__ tx_a,
              const float* __restrict__ ty_a,
              float* __restrict__ out) {
    __shared__ float buf[LP_ * LP_];             // 129 x 129 floats, ~65 KiB

    const int plane = blockIdx.x;                // 0 .. B_*D_-1
    const float* __restrict__ img = fm + (size_t)plane * (H_ * W_);
    float* __restrict__ op = out + (size_t)plane * (H_ * W_);
    const int tid = threadIdx.x;

    // ---- stage plane -> padded LDS via global_load_lds (size=4) ----
    // chunk c (0..255) = 64 consecutive floats of one half-row; LDS dest is
    // wave-uniform base + lane*4 (linear within the chunk, pad untouched).
    {
        const int wid  = tid >> 6;               // 0..7
        const int lane = tid & 63;
#pragma unroll
        for (int j = 0; j < 32; ++j) {
            const int c    = wid * 32 + j;
            const int row  = c >> 1;
            const int half = c & 1;
            const float* g = img + c * 64 + lane;
            __builtin_amdgcn_global_load_lds(
                (const __attribute__((address_space(1))) unsigned int*)g,
                (__attribute__((address_space(3))) unsigned int*)&buf[row * LP_ + half * 64],
                4, 0, 0);
        }
    }
    // zero pads: column 128 of rows 0..127, all 129 entries of row 128 —
    // bilinear taps read them unconditionally with weight exactly 0.
    if (tid < H_)  buf[tid * LP_ + W_] = 0.0f;
    if (tid < LP_) buf[H_ * LP_ + tid] = 0.0f;

    const float sc = sc_a[plane];
    const float cc = c_a[plane];
    const float ss = s_a[plane];
    const float tx = tx_a[plane];
    const float ty = ty_a[plane];

    // Fold normalized->pixel mapping: x = w*ax + h*bx + cx (align_corners=F):
    const float gstep = 2.0f / (float)(W_ - 1);
    const float k64 = (float)W_ * 0.5f;                  // 64
    const float ax =  cc * sc * gstep * k64;
    const float bx = -ss * sc * gstep * k64;
    const float cx = (tx - cc * sc + ss * sc + 1.0f) * k64 - 0.5f;
    const float ay =  ss * sc * gstep * k64;
    const float by =  cc * sc * gstep * k64;
    const float cy = (ty - ss * sc - cc * sc + 1.0f) * k64 - 0.5f;

    // Per-thread base pixel (h0 = tid>>7, w0 = tid&127); iteration it adds
    // exactly 4 rows (512 threads / 128 cols): x_it = xb + it*dx4.
    const int h0 = tid >> 7;
    const int w0 = tid & (W_ - 1);
    const float xb = fmaf((float)w0, ax, fmaf((float)h0, bx, cx));
    const float yb = fmaf((float)w0, ay, fmaf((float)h0, by, cy));
    const float dx4 = 4.0f * bx;
    const float dy4 = 4.0f * by;

    __syncthreads();   // drains the global_load_lds vmcnt traffic

    // ---- 32 px/thread in 4 batches of 8 pixels; sched_barrier(0) splits
    //      load-issue phase from use phase so reads stay hoisted ----
#pragma unroll
    for (int b8 = 0; b8 < 4; ++b8) {
        float wxv[8], wyv[8];
        float v00[8], v01[8], v10[8], v11[8];

        // phase A: addresses + issue all 32 taps (16x ds_read2_b32)
#pragma unroll
        for (int u = 0; u < 8; ++u) {
            const float it = (float)(b8 * 8 + u);
            float x = fmaf(it, dx4, xb);
            float y = fmaf(it, dy4, yb);
            x = fminf(fmaxf(x, 0.0f), (float)(W_ - 1));   // border padding
            y = fminf(fmaxf(y, 0.0f), (float)(H_ - 1));
            const float x0f = floorf(x);
            const float y0f = floorf(y);
            wxv[u] = x - x0f;
            wyv[u] = y - y0f;
            // exact: y0f*129 + x0f <= 16510 < 2^24
            const int base = (int)fmaf(y0f, (float)LP_, x0f);
            v00[u] = buf[base];
            v01[u] = buf[base + 1];           // weight 0 when x at border
            v10[u] = buf[base + LP_];         // weight 0 when y at border
            v11[u] = buf[base + LP_ + 1];
        }

        // scheduler fence: nothing (incl. the ds_reads above) may cross.
        __builtin_amdgcn_sched_barrier(0);

        // phase B: lerps + coalesced stores
#pragma unroll
        for (int u = 0; u < 8; ++u) {
            const int px = (b8 * 8 + u) * 512 + tid;
            const float top = v00[u] + wxv[u] * (v01[u] - v00[u]);
            const float bot = v10[u] + wxv[u] * (v11[u] - v10[u]);
            op[px] = top + wyv[u] * (bot - top);
        }
    }
}

extern "C" void kernel_launch(void* const* d_in, const int* in_sizes, int n_in,
                              void* d_out, int out_size, void* d_ws, size_t ws_size,
                              hipStream_t stream) {
    const float* feature_map = (const float*)d_in[0];
    const float* para_code   = (const float*)d_in[1];
    const float* W1 = (const float*)d_in[2];
    const float* b1 = (const float*)d_in[3];
    const float* Ws = (const float*)d_in[4];
    const float* bs = (const float*)d_in[5];
    const float* Wr = (const float*)d_in[6];
    const float* br = (const float*)d_in[7];
    const float* Wt = (const float*)d_in[8];
    const float* bt = (const float*)d_in[9];
    float* out = (float*)d_out;

    // Workspace layout (floats): sc | c | s | tx | ty (each B_*D_)
    float* ws_f = (float*)d_ws;
    float* sc_a  = ws_f;
    float* c_a   = sc_a + B_ * D_;
    float* s_a   = c_a  + B_ * D_;
    float* tx_a  = s_a  + B_ * D_;
    float* ty_a  = tx_a + B_ * D_;

    k_params<<<dim3(B_, 2), PC_, 0, stream>>>(para_code, W1, b1, Ws, bs, Wr, br,
                                              Wt, bt, sc_a, c_a, s_a, tx_a, ty_a);
    k_sample<<<B_ * D_, 512, 0, stream>>>(feature_map, sc_a, c_a, s_a, tx_a, ty_a, out);
}

// Round 11
// 78.664 us; speedup vs baseline: 1.0567x; 1.0567x over previous
//
#include <hip/hip_runtime.h>
#include <math.h>

// Problem shape (fixed by reference setup_inputs):
//   feature_map: (B=8, D=256, H=128, W=128) fp32
//   para_code:   (8, 256)
//   W1 (256,256) b1(256) | Ws (256,256) bs(256) | Wr (256,256) br(256)
//   Wt (256,512) bt(512)
// Output: (8, 256, 128, 128) fp32

#define B_  8
#define D_  256
#define H_  128
#define W_  128
#define PC_ 256
#define PI_F 3.14159f
#define LPU_ 130  // padded bf16 LDS row stride (ushorts): row step = 260 B =
                  // 65 dwords == 1 mod 32 banks -> rotation (column-step)
                  // gathers stay conflict-free, same property as fp32 LP=129.

// ------------- Kernel 1: fused p = relu(para@W1+b1) -> heads ----------------
__global__ void k_params(const float* __restrict__ para,
                         const float* __restrict__ W1, const float* __restrict__ b1,
                         const float* __restrict__ Ws, const float* __restrict__ bs,
                         const float* __restrict__ Wr, const float* __restrict__ br,
                         const float* __restrict__ Wt, const float* __restrict__ bt,
                         float* __restrict__ sc_o, float* __restrict__ c_o,
                         float* __restrict__ s_o,  float* __restrict__ tx_o,
                         float* __restrict__ ty_o) {
    __shared__ float sp[PC_];   // para row
    __shared__ float pp[PC_];   // relu'd hidden
    const int b = blockIdx.x;
    const int which = blockIdx.y;
    const int d = threadIdx.x;
    sp[d] = para[b * PC_ + d];
    __syncthreads();

    float acc = b1[d];
#pragma unroll 8
    for (int k = 0; k < PC_; ++k) {
        acc = fmaf(sp[k], W1[k * PC_ + d], acc);
    }
    pp[d] = fmaxf(acc, 0.0f);
    __syncthreads();

    const int o = b * D_ + d;
    if (which == 0) {
        float as = bs[d];
        float ar = br[d];
#pragma unroll 8
        for (int k = 0; k < PC_; ++k) {
            const float pk = pp[k];
            as = fmaf(pk, Ws[k * PC_ + d], as);
            ar = fmaf(pk, Wr[k * PC_ + d], ar);
        }
        const float scale = 2.0f / (1.0f + expf(-as));      // sigmoid * 2
        const float ang   = tanhf(ar) * PI_F;
        sc_o[o] = scale;
        c_o[o]  = cosf(ang);
        s_o[o]  = sinf(ang);
    } else {
        const float2* __restrict__ Wt2 = (const float2*)Wt;  // (256,256) float2
        float t0 = bt[2 * d];
        float t1 = bt[2 * d + 1];
#pragma unroll 8
        for (int k = 0; k < PC_; ++k) {
            const float pk = pp[k];
            const float2 wt = Wt2[k * PC_ + d];
            t0 = fmaf(pk, wt.x, t0);
            t1 = fmaf(pk, wt.y, t1);
        }
        tx_o[o] = tanhf(t0);
        ty_o[o] = tanhf(t1);
    }
}

// bf16 round-to-nearest-even (values are finite normals; no NaN path needed)
__device__ __forceinline__ unsigned short bf16_rne(float f) {
    unsigned int u = __float_as_uint(f);
    u += 0x7FFFu + ((u >> 16) & 1u);
    return (unsigned short)(u >> 16);
}

// ------------- Kernel 2: affine grid-sample via bf16 LDS plane --------------
// Rounds 3-10 invariant: every fp32-LDS structure lands ~84us with HBM duty
// ~50% — the 67KB buffer caps residency at 2 blocks/CU whose stage/compute
// phases align, so HBM reads and compute never overlap (84 ~= 2x the 42us
// floor). Fix: bf16 plane = 33.5KB -> 4 independent blocks/CU, 32 waves/CU
// (full slots). Four blocks self-stagger -> continuous HBM streaming; 8
// waves/SIMD hide LDS latency. Taps: 4x ds_read_u16 + shift-decode; RNE
// bf16 adds <=0.011 abs error (threshold 0.1056, current 0.0156).
__global__ __launch_bounds__(512, 8)
void k_sample(const float* __restrict__ fm,
              const float* __restrict__ sc_a, const float* __restrict__ c_a,
              const float* __restrict__ s_a,  const float* __restrict__ tx_a,
              const float* __restrict__ ty_a,
              float* __restrict__ out) {
    __shared__ unsigned short lds[129 * LPU_];   // 33,540 B -> 4 blocks/CU

    const int plane = blockIdx.x;                // 0 .. B_*D_-1
    const float* __restrict__ img = fm + (size_t)plane * (H_ * W_);
    float* __restrict__ op = out + (size_t)plane * (H_ * W_);
    const int tid = threadIdx.x;

    // ---- stage plane -> bf16 padded LDS (float4 loads, packed b32 writes) --
    {
        const float4* __restrict__ src = (const float4*)img;
#pragma unroll
        for (int j = 0; j < 8; ++j) {
            const int e4 = j * 512 + tid;        // float4 index 0..4095
            const float4 v = src[e4];
            const int h = e4 >> 5;               // (e4*4) >> 7
            const int w = (e4 & 31) * 4;
            unsigned int lo = (unsigned int)bf16_rne(v.x) |
                              ((unsigned int)bf16_rne(v.y) << 16);
            unsigned int hi = (unsigned int)bf16_rne(v.z) |
                              ((unsigned int)bf16_rne(v.w) << 16);
            // (h*130 + w)*2 bytes: w % 4 == 0 -> 4B aligned
            unsigned int* dst = (unsigned int*)&lds[h * LPU_ + w];
            dst[0] = lo;
            dst[1] = hi;
        }
    }
    // zero pads: col 128 of rows 0..128, and all of row 128 (taps read x0+1 /
    // y0+1 unconditionally; their weights are exactly 0 at the border)
    if (tid < H_ + 1)  lds[tid * LPU_ + W_] = 0;
    if (tid < LPU_)    lds[H_ * LPU_ + tid] = 0;

    const float sc = sc_a[plane];
    const float cc = c_a[plane];
    const float ss = s_a[plane];
    const float tx = tx_a[plane];
    const float ty = ty_a[plane];

    // Fold normalized->pixel mapping: x = w*ax + h*bx + cx (align_corners=F):
    const float gstep = 2.0f / (float)(W_ - 1);
    const float k64 = (float)W_ * 0.5f;                  // 64
    const float ax =  cc * sc * gstep * k64;
    const float bx = -ss * sc * gstep * k64;
    const float cx = (tx - cc * sc + ss * sc + 1.0f) * k64 - 0.5f;
    const float ay =  ss * sc * gstep * k64;
    const float by =  cc * sc * gstep * k64;
    const float cy = (ty - ss * sc - cc * sc + 1.0f) * k64 - 0.5f;

    // Per-thread base pixel (h0 = tid>>7, w0 = tid&127); iteration adds
    // exactly 4 rows (512 threads / 128 cols): x_it = xb + it*dx4.
    const int h0 = tid >> 7;
    const int w0 = tid & (W_ - 1);
    const float xb = fmaf((float)w0, ax, fmaf((float)h0, bx, cx));
    const float yb = fmaf((float)w0, ay, fmaf((float)h0, by, cy));
    const float dx4 = 4.0f * bx;
    const float dy4 = 4.0f * by;

    __syncthreads();

    // ---- 32 px/thread in 8 batches of 4 pixels (fits 64-VGPR budget) ----
#pragma unroll
    for (int b4 = 0; b4 < 8; ++b4) {
        float wxv[4], wyv[4];
        unsigned short t00[4], t01[4], t10[4], t11[4];

        // phase A: addresses + issue all 16 u16 taps
#pragma unroll
        for (int u = 0; u < 4; ++u) {
            const float it = (float)(b4 * 4 + u);
            float x = fmaf(it, dx4, xb);
            float y = fmaf(it, dy4, yb);
            x = fminf(fmaxf(x, 0.0f), (float)(W_ - 1));   // border padding
            y = fminf(fmaxf(y, 0.0f), (float)(H_ - 1));
            const float x0f = floorf(x);
            const float y0f = floorf(y);
            wxv[u] = x - x0f;
            wyv[u] = y - y0f;
            // exact: y0f*130 + x0f <= 16768 < 2^24
            const int base = (int)fmaf(y0f, (float)LPU_, x0f);
            t00[u] = lds[base];
            t01[u] = lds[base + 1];           // weight 0 when x at border
            t10[u] = lds[base + LPU_];        // weight 0 when y at border
            t11[u] = lds[base + LPU_ + 1];
        }

        __builtin_amdgcn_sched_barrier(0);

        // phase B: decode + lerps + coalesced stores
#pragma unroll
        for (int u = 0; u < 4; ++u) {
            const float v00 = __uint_as_float((unsigned int)t00[u] << 16);
            const float v01 = __uint_as_float((unsigned int)t01[u] << 16);
            const float v10 = __uint_as_float((unsigned int)t10[u] << 16);
            const float v11 = __uint_as_float((unsigned int)t11[u] << 16);
            const int px = (b4 * 4 + u) * 512 + tid;
            const float top = v00 + wxv[u] * (v01 - v00);
            const float bot = v10 + wxv[u] * (v11 - v10);
            op[px] = top + wyv[u] * (bot - top);
        }
    }
}

extern "C" void kernel_launch(void* const* d_in, const int* in_sizes, int n_in,
                              void* d_out, int out_size, void* d_ws, size_t ws_size,
                              hipStream_t stream) {
    const float* feature_map = (const float*)d_in[0];
    const float* para_code   = (const float*)d_in[1];
    const float* W1 = (const float*)d_in[2];
    const float* b1 = (const float*)d_in[3];
    const float* Ws = (const float*)d_in[4];
    const float* bs = (const float*)d_in[5];
    const float* Wr = (const float*)d_in[6];
    const float* br = (const float*)d_in[7];
    const float* Wt = (const float*)d_in[8];
    const float* bt = (const float*)d_in[9];
    float* out = (float*)d_out;

    // Workspace layout (floats): sc | c | s | tx | ty (each B_*D_)
    float* ws_f = (float*)d_ws;
    float* sc_a  = ws_f;
    float* c_a   = sc_a + B_ * D_;
    float* s_a   = c_a  + B_ * D_;
    float* tx_a  = s_a  + B_ * D_;
    float* ty_a  = tx_a + B_ * D_;

    k_params<<<dim3(B_, 2), PC_, 0, stream>>>(para_code, W1, b1, Ws, bs, Wr, br,
                                              Wt, bt, sc_a, c_a, s_a, tx_a, ty_a);
    k_sample<<<B_ * D_, 512, 0, stream>>>(feature_map, sc_a, c_a, s_a, tx_a, ty_a, out);
}